// Round 1
// baseline (233.619 us; speedup 1.0000x reference)
//
#include <hip/hip_runtime.h>
#include <hip/hip_bf16.h>

#define NTOK   8192
#define TOPK   2
#define NEXP   8
#define KDIM   1024
#define NDIM   1024
#define MOUT   (NTOK * TOPK)        // 16384 dispatched rows
#define BM     128
#define BN     128
#define BK     64
#define MAXT   (MOUT / BM + NEXP)   // 136 tile slots (expert-boundary padding)
#define ROWTOK 1024                 // int offset of row_token[] in ws

typedef unsigned short ushort_t;
typedef __attribute__((ext_vector_type(8))) short short8;
typedef __attribute__((ext_vector_type(4))) float floatx4;

// ---------------------------------------------------------------------------
// Setup: invert scatter_index -> row_token; build expert tile table.
// ws int layout: [0]=n_tiles; [16+3t]={row0,rows,expert}; [ROWTOK+s]=token(s)
// ---------------------------------------------------------------------------
__global__ void moe_setup(const int* __restrict__ scatter,
                          const int* __restrict__ splits,
                          int* __restrict__ ws) {
  int tid = blockIdx.x * blockDim.x + threadIdx.x;
  if (tid < MOUT) {
    int s = scatter[tid];           // flat slot tid -> output row s
    ws[ROWTOK + s] = tid / TOPK;    // token of that slot
  }
  if (tid == 0) {
    int nt = 0, off = 0;
    for (int e = 0; e < NEXP; ++e) {
      int end = off + splits[e];
      for (int r0 = off; r0 < end; r0 += BM) {
        ws[16 + 3 * nt + 0] = r0;
        ws[16 + 3 * nt + 1] = (end - r0 < BM) ? (end - r0) : BM;
        ws[16 + 3 * nt + 2] = e;
        ++nt;
      }
      off = end;
    }
    ws[0] = nt;
    for (int t = nt; t < MAXT; ++t) {   // ws is re-poisoned: must zero unused slots
      ws[16 + 3 * t + 0] = 0;
      ws[16 + 3 * t + 1] = 0;
      ws[16 + 3 * t + 2] = 0;
    }
  }
}

// ---------------------------------------------------------------------------
// Grouped GEMM: C[row0:row0+rows, c0:c0+128] = gather(x) @ W[e].T
// fp32 in -> bf16 MFMA (16x16x32) -> fp32 out. XOR-swizzled LDS (conflict-free).
// ---------------------------------------------------------------------------
__global__ __launch_bounds__(256)
void moe_gemm(const float* __restrict__ x,
              const float* __restrict__ w,
              const int* __restrict__ ws,
              float* __restrict__ out) {
  __shared__ ushort_t As[BM * BK];   // 16 KiB bf16
  __shared__ ushort_t Bs[BN * BK];   // 16 KiB bf16

  const int slot = blockIdx.x;
  const int rows = ws[16 + 3 * slot + 1];
  if (rows == 0) return;             // unused slot (uniform exit)
  const int row0 = ws[16 + 3 * slot + 0];
  const int e    = ws[16 + 3 * slot + 2];
  const int c0   = blockIdx.y * BN;

  const int tid  = threadIdx.x;
  const int lane = tid & 63;
  const int wave = tid >> 6;
  const int wm   = (wave >> 1) * 64; // wave's 64x64 sub-tile origin
  const int wn   = (wave & 1) * 64;
  const int quad = lane >> 4;
  const int l16  = lane & 15;

  const int* __restrict__ row_token = ws + ROWTOK;

  // Staging map: thread covers float4 index f4 (0..15) of rows rbase+16i.
  const int f4    = tid & 15;
  const int rbase = tid >> 4;                       // 0..15
  const int swz   = (f4 >> 1) ^ (rbase & 7);        // (rbase+16i)&7 == rbase&7
  const int wroff = rbase * BK + swz * 8 + (f4 & 1) * 4;  // ushort offset

  const float* __restrict__ wb = w + ((size_t)e * NDIM + c0) * KDIM;

  // Gathered A row pointers (token indirection), zero-fill tail rows.
  const float* pA[8];
#pragma unroll
  for (int i = 0; i < 8; ++i) {
    int r = rbase + i * 16;
    pA[i] = (r < rows) ? (x + (size_t)row_token[row0 + r] * KDIM + f4 * 4)
                       : nullptr;
  }
  const float* pB0 = wb + (size_t)rbase * KDIM + f4 * 4;

  floatx4 zero = {0.f, 0.f, 0.f, 0.f};
  floatx4 acc[4][4];
#pragma unroll
  for (int i = 0; i < 4; ++i)
#pragma unroll
    for (int j = 0; j < 4; ++j) acc[i][j] = zero;

#pragma unroll 1
  for (int kk = 0; kk < KDIM; kk += BK) {
    // ---- stage A (gather + fp32->bf16 pack) ----
#pragma unroll
    for (int i = 0; i < 8; ++i) {
      float4 v = {0.f, 0.f, 0.f, 0.f};
      if (pA[i]) v = *(const float4*)(pA[i] + kk);
      union { __hip_bfloat162 h; unsigned int u; } lo, hi;
      lo.h = __float22bfloat162_rn(make_float2(v.x, v.y));
      hi.h = __float22bfloat162_rn(make_float2(v.z, v.w));
      uint2 u2; u2.x = lo.u; u2.y = hi.u;
      *(uint2*)(&As[wroff + i * 16 * BK]) = u2;
    }
    // ---- stage B ----
#pragma unroll
    for (int i = 0; i < 8; ++i) {
      float4 v = *(const float4*)(pB0 + (size_t)i * 16 * KDIM + kk);
      union { __hip_bfloat162 h; unsigned int u; } lo, hi;
      lo.h = __float22bfloat162_rn(make_float2(v.x, v.y));
      hi.h = __float22bfloat162_rn(make_float2(v.z, v.w));
      uint2 u2; u2.x = lo.u; u2.y = hi.u;
      *(uint2*)(&Bs[wroff + i * 16 * BK]) = u2;
    }
    __syncthreads();

    // ---- MFMA: 2 k-steps x 4x4 tiles of 16x16x32 ----
#pragma unroll
    for (int k2 = 0; k2 < 2; ++k2) {
      short8 af[4], bf[4];
#pragma unroll
      for (int i = 0; i < 4; ++i) {
        int m = wm + i * 16 + l16;
        int c = k2 * 4 + quad;            // 16B chunk within row
        af[i] = *(const short8*)(&As[m * BK + (c ^ (m & 7)) * 8]);
      }
#pragma unroll
      for (int j = 0; j < 4; ++j) {
        int n = wn + j * 16 + l16;
        int c = k2 * 4 + quad;
        bf[j] = *(const short8*)(&Bs[n * BK + (c ^ (n & 7)) * 8]);
      }
#pragma unroll
      for (int i = 0; i < 4; ++i)
#pragma unroll
        for (int j = 0; j < 4; ++j)
          acc[i][j] = __builtin_amdgcn_mfma_f32_16x16x32_bf16(af[i], bf[j],
                                                              acc[i][j], 0, 0, 0);
    }
    __syncthreads();
  }

  // ---- epilogue: C/D layout col=lane&15, row=quad*4+reg (m89-verified) ----
#pragma unroll
  for (int i = 0; i < 4; ++i) {
#pragma unroll
    for (int r = 0; r < 4; ++r) {
      int lrow = wm + i * 16 + quad * 4 + r;
      if (lrow < rows) {
        float* o = out + (size_t)(row0 + lrow) * NDIM + c0 + wn + l16;
#pragma unroll
        for (int j = 0; j < 4; ++j) o[j * 16] = acc[i][j][r];
      }
    }
  }
}

// ---------------------------------------------------------------------------
extern "C" void kernel_launch(void* const* d_in, const int* in_sizes, int n_in,
                              void* d_out, int out_size, void* d_ws, size_t ws_size,
                              hipStream_t stream) {
  const float* x       = (const float*)d_in[0];   // [8192,1024] f32
  const float* weights = (const float*)d_in[1];   // [8,1024,1024] f32
  const int*   scatter = (const int*)d_in[2];     // [8192,2] i32
  const int*   splits  = (const int*)d_in[3];     // [8] i32
  float*       out     = (float*)d_out;           // [16384,1024] f32
  int*         ws      = (int*)d_ws;

  moe_setup<<<dim3(MOUT / 256), dim3(256), 0, stream>>>(scatter, splits, ws);
  moe_gemm<<<dim3(MAXT, NDIM / BN), dim3(256), 0, stream>>>(x, weights, ws, out);
}

// Round 2
// 190.691 us; speedup vs baseline: 1.2251x; 1.2251x over previous
//
#include <hip/hip_runtime.h>
#include <hip/hip_bf16.h>

#define NTOK   8192
#define TOPK   2
#define NEXP   8
#define KDIM   1024
#define NDIM   1024
#define MOUT   (NTOK * TOPK)        // 16384 dispatched rows
#define BM     128
#define BN     128
#define BK     64
#define MAXT   (MOUT / BM + NEXP)   // 136 tile slots (expert-boundary padding)
#define ROWTOK 1024                 // int offset of row_token[] in ws

// ws byte layout (fast path):
//   [0, 4KiB)        tile table (ints, offset 16)
//   [4KiB, 68KiB)    row_token (16384 ints, int offset 1024)
//   [128KiB, +16MiB) x_bf16  [8192,1024]
//   [next, +16MiB)   w_bf16  [8,1024,1024]
#define XB_OFF   (128 * 1024)
#define XB_BYTES (NTOK * KDIM * 2)
#define WB_OFF   (XB_OFF + XB_BYTES)
#define WB_BYTES (NEXP * NDIM * KDIM * 2)
#define WS_NEED  ((size_t)(WB_OFF + WB_BYTES))

typedef unsigned short ushort_t;
typedef __attribute__((ext_vector_type(8))) short short8;
typedef __attribute__((ext_vector_type(4))) float floatx4;
typedef __attribute__((address_space(1))) const unsigned int gu32;
typedef __attribute__((address_space(3))) unsigned int lu32;

// ---------------------------------------------------------------------------
// Setup: invert scatter_index -> row_token; build expert tile table.
// ---------------------------------------------------------------------------
__global__ void moe_setup(const int* __restrict__ scatter,
                          const int* __restrict__ splits,
                          int* __restrict__ ws) {
  int tid = blockIdx.x * blockDim.x + threadIdx.x;
  if (tid < MOUT) {
    int s = scatter[tid];           // flat slot tid -> output row s
    ws[ROWTOK + s] = tid / TOPK;    // token of that slot
  }
  if (tid == 0) {
    int nt = 0, off = 0;
    for (int e = 0; e < NEXP; ++e) {
      int end = off + splits[e];
      for (int r0 = off; r0 < end; r0 += BM) {
        ws[16 + 3 * nt + 0] = r0;
        ws[16 + 3 * nt + 1] = (end - r0 < BM) ? (end - r0) : BM;
        ws[16 + 3 * nt + 2] = e;
        ++nt;
      }
      off = end;
    }
    ws[0] = nt;
    for (int t = nt; t < MAXT; ++t) {
      ws[16 + 3 * t + 0] = 0;
      ws[16 + 3 * t + 1] = 0;
      ws[16 + 3 * t + 2] = 0;
    }
  }
}

// ---------------------------------------------------------------------------
// fp32 -> bf16 grid-stride convert (float4 in, uint2 out)
// ---------------------------------------------------------------------------
__global__ __launch_bounds__(256)
void convert_bf16(const float* __restrict__ in, ushort_t* __restrict__ outb,
                  int n4) {
  int idx = blockIdx.x * 256 + threadIdx.x;
  for (int i = idx; i < n4; i += gridDim.x * 256) {
    float4 v = ((const float4*)in)[i];
    union { __hip_bfloat162 h; unsigned int u; } lo, hi;
    lo.h = __float22bfloat162_rn(make_float2(v.x, v.y));
    hi.h = __float22bfloat162_rn(make_float2(v.z, v.w));
    uint2 u2; u2.x = lo.u; u2.y = hi.u;
    ((uint2*)outb)[i] = u2;
  }
}

// ---------------------------------------------------------------------------
// Fast grouped GEMM: bf16 inputs, global_load_lds width-16 staging.
// A-side gather (token indirection) rides the per-lane global address.
// ---------------------------------------------------------------------------
__global__ __launch_bounds__(256)
void moe_gemm_fast(const ushort_t* __restrict__ xb,   // [8192,1024] bf16
                   const ushort_t* __restrict__ wbm,  // [8,1024,1024] bf16
                   const int* __restrict__ ws,
                   float* __restrict__ out) {
  __shared__ ushort_t As[BM * BK];   // 16 KiB, row-major [128][64]
  __shared__ ushort_t Bs[BN * BK];   // 16 KiB

  const int slot = blockIdx.x;
  const int rows = ws[16 + 3 * slot + 1];
  if (rows == 0) return;
  const int row0 = ws[16 + 3 * slot + 0];
  const int e    = ws[16 + 3 * slot + 2];
  const int c0   = blockIdx.y * BN;

  const int tid  = threadIdx.x;
  const int lane = tid & 63;
  const int wave = tid >> 6;
  const int wm   = (wave >> 1) * 64;
  const int wn   = (wave & 1) * 64;
  const int quad = lane >> 4;
  const int l16  = lane & 15;

  const int* __restrict__ row_token = ws + ROWTOK;

  // Staging: wave covers rows [wave*32, wave*32+32) of each tile.
  // Instr t (0..3): 8 rows; lane -> row wave*32+t*8+lane/8, chunk (lane&7)*8 elems.
  const int lrow8  = lane >> 3;
  const int lchunk = lane & 7;

  const ushort_t* aptr[4];
  const ushort_t* bptr[4];
#pragma unroll
  for (int t = 0; t < 4; ++t) {
    int r  = wave * 32 + t * 8 + lrow8;
    int rc = (r < rows) ? r : (rows - 1);          // clamp tail to a valid row
    aptr[t] = xb + (size_t)row_token[row0 + rc] * KDIM + lchunk * 8;
    bptr[t] = wbm + ((size_t)e * NDIM + c0 + r) * KDIM + lchunk * 8;
  }

  floatx4 zero = {0.f, 0.f, 0.f, 0.f};
  floatx4 acc[4][4];
#pragma unroll
  for (int i = 0; i < 4; ++i)
#pragma unroll
    for (int j = 0; j < 4; ++j) acc[i][j] = zero;

#pragma unroll 1
  for (int kk = 0; kk < KDIM; kk += BK) {
#pragma unroll
    for (int t = 0; t < 4; ++t) {
      __builtin_amdgcn_global_load_lds(
          (gu32*)(const void*)(aptr[t] + kk),
          (lu32*)(void*)(As + (wave * 32 + t * 8) * BK), 16, 0, 0);
      __builtin_amdgcn_global_load_lds(
          (gu32*)(const void*)(bptr[t] + kk),
          (lu32*)(void*)(Bs + (wave * 32 + t * 8) * BK), 16, 0, 0);
    }
    __syncthreads();

#pragma unroll
    for (int k2 = 0; k2 < 2; ++k2) {
      short8 af[4], bf[4];
#pragma unroll
      for (int i = 0; i < 4; ++i)
        af[i] = *(const short8*)(&As[(wm + i * 16 + l16) * BK + (k2 * 4 + quad) * 8]);
#pragma unroll
      for (int j = 0; j < 4; ++j)
        bf[j] = *(const short8*)(&Bs[(wn + j * 16 + l16) * BK + (k2 * 4 + quad) * 8]);
#pragma unroll
      for (int i = 0; i < 4; ++i)
#pragma unroll
        for (int j = 0; j < 4; ++j)
          acc[i][j] = __builtin_amdgcn_mfma_f32_16x16x32_bf16(af[i], bf[j],
                                                              acc[i][j], 0, 0, 0);
    }
    __syncthreads();
  }

#pragma unroll
  for (int i = 0; i < 4; ++i) {
#pragma unroll
    for (int r = 0; r < 4; ++r) {
      int lrow = wm + i * 16 + quad * 4 + r;
      if (lrow < rows) {
        float* o = out + (size_t)(row0 + lrow) * NDIM + c0 + wn + l16;
#pragma unroll
        for (int j = 0; j < 4; ++j) o[j * 16] = acc[i][j][r];
      }
    }
  }
}

// ---------------------------------------------------------------------------
// Fallback (round-1 fused convert) if ws is too small for bf16 staging bufs.
// ---------------------------------------------------------------------------
__global__ __launch_bounds__(256)
void moe_gemm_fallback(const float* __restrict__ x,
                       const float* __restrict__ w,
                       const int* __restrict__ ws,
                       float* __restrict__ out) {
  __shared__ ushort_t As[BM * BK];
  __shared__ ushort_t Bs[BN * BK];

  const int slot = blockIdx.x;
  const int rows = ws[16 + 3 * slot + 1];
  if (rows == 0) return;
  const int row0 = ws[16 + 3 * slot + 0];
  const int e    = ws[16 + 3 * slot + 2];
  const int c0   = blockIdx.y * BN;

  const int tid  = threadIdx.x;
  const int lane = tid & 63;
  const int wave = tid >> 6;
  const int wm   = (wave >> 1) * 64;
  const int wn   = (wave & 1) * 64;
  const int quad = lane >> 4;
  const int l16  = lane & 15;

  const int* __restrict__ row_token = ws + ROWTOK;

  const int f4    = tid & 15;
  const int rbase = tid >> 4;
  const int swz   = (f4 >> 1) ^ (rbase & 7);
  const int wroff = rbase * BK + swz * 8 + (f4 & 1) * 4;

  const float* __restrict__ wb = w + ((size_t)e * NDIM + c0) * KDIM;
  const float* pA[8];
#pragma unroll
  for (int i = 0; i < 8; ++i) {
    int r = rbase + i * 16;
    pA[i] = (r < rows) ? (x + (size_t)row_token[row0 + r] * KDIM + f4 * 4)
                       : nullptr;
  }
  const float* pB0 = wb + (size_t)rbase * KDIM + f4 * 4;

  floatx4 zero = {0.f, 0.f, 0.f, 0.f};
  floatx4 acc[4][4];
#pragma unroll
  for (int i = 0; i < 4; ++i)
#pragma unroll
    for (int j = 0; j < 4; ++j) acc[i][j] = zero;

#pragma unroll 1
  for (int kk = 0; kk < KDIM; kk += BK) {
#pragma unroll
    for (int i = 0; i < 8; ++i) {
      float4 v = {0.f, 0.f, 0.f, 0.f};
      if (pA[i]) v = *(const float4*)(pA[i] + kk);
      union { __hip_bfloat162 h; unsigned int u; } lo, hi;
      lo.h = __float22bfloat162_rn(make_float2(v.x, v.y));
      hi.h = __float22bfloat162_rn(make_float2(v.z, v.w));
      uint2 u2; u2.x = lo.u; u2.y = hi.u;
      *(uint2*)(&As[wroff + i * 16 * BK]) = u2;
    }
#pragma unroll
    for (int i = 0; i < 8; ++i) {
      float4 v = *(const float4*)(pB0 + (size_t)i * 16 * KDIM + kk);
      union { __hip_bfloat162 h; unsigned int u; } lo, hi;
      lo.h = __float22bfloat162_rn(make_float2(v.x, v.y));
      hi.h = __float22bfloat162_rn(make_float2(v.z, v.w));
      uint2 u2; u2.x = lo.u; u2.y = hi.u;
      *(uint2*)(&Bs[wroff + i * 16 * BK]) = u2;
    }
    __syncthreads();
#pragma unroll
    for (int k2 = 0; k2 < 2; ++k2) {
      short8 af[4], bf[4];
#pragma unroll
      for (int i = 0; i < 4; ++i) {
        int m = wm + i * 16 + l16;
        af[i] = *(const short8*)(&As[m * BK + ((k2 * 4 + quad) ^ (m & 7)) * 8]);
      }
#pragma unroll
      for (int j = 0; j < 4; ++j) {
        int n = wn + j * 16 + l16;
        bf[j] = *(const short8*)(&Bs[n * BK + ((k2 * 4 + quad) ^ (n & 7)) * 8]);
      }
#pragma unroll
      for (int i = 0; i < 4; ++i)
#pragma unroll
        for (int j = 0; j < 4; ++j)
          acc[i][j] = __builtin_amdgcn_mfma_f32_16x16x32_bf16(af[i], bf[j],
                                                              acc[i][j], 0, 0, 0);
    }
    __syncthreads();
  }

#pragma unroll
  for (int i = 0; i < 4; ++i) {
#pragma unroll
    for (int r = 0; r < 4; ++r) {
      int lrow = wm + i * 16 + quad * 4 + r;
      if (lrow < rows) {
        float* o = out + (size_t)(row0 + lrow) * NDIM + c0 + wn + l16;
#pragma unroll
        for (int j = 0; j < 4; ++j) o[j * 16] = acc[i][j][r];
      }
    }
  }
}

// ---------------------------------------------------------------------------
extern "C" void kernel_launch(void* const* d_in, const int* in_sizes, int n_in,
                              void* d_out, int out_size, void* d_ws, size_t ws_size,
                              hipStream_t stream) {
  const float* x       = (const float*)d_in[0];   // [8192,1024] f32
  const float* weights = (const float*)d_in[1];   // [8,1024,1024] f32
  const int*   scatter = (const int*)d_in[2];     // [8192,2] i32
  const int*   splits  = (const int*)d_in[3];     // [8] i32
  float*       out     = (float*)d_out;           // [16384,1024] f32
  int*         ws      = (int*)d_ws;

  moe_setup<<<dim3(MOUT / 256), dim3(256), 0, stream>>>(scatter, splits, ws);

  if (ws_size >= WS_NEED) {
    ushort_t* xb = (ushort_t*)((char*)d_ws + XB_OFF);
    ushort_t* wb = (ushort_t*)((char*)d_ws + WB_OFF);
    convert_bf16<<<dim3(1024), dim3(256), 0, stream>>>(x, xb, NTOK * KDIM / 4);
    convert_bf16<<<dim3(1024), dim3(256), 0, stream>>>(weights, wb,
                                                       NEXP * NDIM * KDIM / 4);
    moe_gemm_fast<<<dim3(MAXT, NDIM / BN), dim3(256), 0, stream>>>(xb, wb, ws, out);
  } else {
    moe_gemm_fallback<<<dim3(MAXT, NDIM / BN), dim3(256), 0, stream>>>(x, weights,
                                                                       ws, out);
  }
}

// Round 3
// 168.425 us; speedup vs baseline: 1.3871x; 1.1322x over previous
//
#include <hip/hip_runtime.h>
#include <hip/hip_bf16.h>

#define NTOK   8192
#define TOPK   2
#define NEXP   8
#define KDIM   1024
#define NDIM   1024
#define MOUT   (NTOK * TOPK)        // 16384 dispatched rows
#define BM     128
#define BN     128
#define BK     64
#define MAXT   (MOUT / BM + NEXP)   // 136 tile slots (expert-boundary padding)
#define ROWTOK 1024                 // int offset of row_token[] in ws

// ws byte layout (fast path):
//   [0, 4KiB)        tile table (ints, offset 16)
//   [4KiB, 68KiB)    row_token (16384 ints, int offset 1024)
//   [128KiB, +16MiB) x_bf16  [8192,1024]
//   [next, +16MiB)   w_bf16  [8,1024,1024]
#define XB_OFF   (128 * 1024)
#define XB_BYTES (NTOK * KDIM * 2)
#define WB_OFF   (XB_OFF + XB_BYTES)
#define WB_BYTES (NEXP * NDIM * KDIM * 2)
#define WS_NEED  ((size_t)(WB_OFF + WB_BYTES))

typedef unsigned short ushort_t;
typedef __attribute__((ext_vector_type(8))) short short8;
typedef __attribute__((ext_vector_type(4))) float floatx4;
typedef __attribute__((address_space(1))) const unsigned int gu32;
typedef __attribute__((address_space(3))) unsigned int lu32;

// ---------------------------------------------------------------------------
// Setup: invert scatter_index -> row_token; build expert tile table.
// ---------------------------------------------------------------------------
__global__ void moe_setup(const int* __restrict__ scatter,
                          const int* __restrict__ splits,
                          int* __restrict__ ws) {
  int tid = blockIdx.x * blockDim.x + threadIdx.x;
  if (tid < MOUT) {
    int s = scatter[tid];           // flat slot tid -> output row s
    ws[ROWTOK + s] = tid / TOPK;    // token of that slot
  }
  if (tid == 0) {
    int nt = 0, off = 0;
    for (int e = 0; e < NEXP; ++e) {
      int end = off + splits[e];
      for (int r0 = off; r0 < end; r0 += BM) {
        ws[16 + 3 * nt + 0] = r0;
        ws[16 + 3 * nt + 1] = (end - r0 < BM) ? (end - r0) : BM;
        ws[16 + 3 * nt + 2] = e;
        ++nt;
      }
      off = end;
    }
    ws[0] = nt;
    for (int t = nt; t < MAXT; ++t) {
      ws[16 + 3 * t + 0] = 0;
      ws[16 + 3 * t + 1] = 0;
      ws[16 + 3 * t + 2] = 0;
    }
  }
}

// ---------------------------------------------------------------------------
// Fused fp32 -> bf16 convert of both x and weights (single launch).
// ---------------------------------------------------------------------------
__global__ __launch_bounds__(256)
void convert_both(const float* __restrict__ x, const float* __restrict__ w,
                  ushort_t* __restrict__ xb, ushort_t* __restrict__ wb) {
  const int N4X = NTOK * KDIM / 4;
  const int N4W = NEXP * NDIM * KDIM / 4;
  int idx = blockIdx.x * 256 + threadIdx.x;
  for (int i = idx; i < N4X + N4W; i += gridDim.x * 256) {
    float4 v = (i < N4X) ? ((const float4*)x)[i] : ((const float4*)w)[i - N4X];
    union { __hip_bfloat162 h; unsigned int u; } lo, hi;
    lo.h = __float22bfloat162_rn(make_float2(v.x, v.y));
    hi.h = __float22bfloat162_rn(make_float2(v.z, v.w));
    uint2 u2; u2.x = lo.u; u2.y = hi.u;
    if (i < N4X) ((uint2*)xb)[i] = u2;
    else         ((uint2*)wb)[i - N4X] = u2;
  }
}

// ---------------------------------------------------------------------------
// Fast grouped GEMM: bf16 inputs, global_load_lds width-16 staging, with
// INVERSE-SWIZZLED global fetch so the (fixed, lane-ordered) LDS layout is
// bank-conflict-free on fragment reads:
//   LDS slot (row r, pos p) holds global chunk p ^ (r&7)   (16B chunks)
//   fragment read of chunk c of row m -> LDS pos c ^ (m&7) -> 2-way max (free)
// ---------------------------------------------------------------------------
__global__ __launch_bounds__(256, 3)
void moe_gemm_fast(const ushort_t* __restrict__ xb,   // [8192,1024] bf16
                   const ushort_t* __restrict__ wbm,  // [8,1024,1024] bf16
                   const int* __restrict__ ws,
                   float* __restrict__ out) {
  __shared__ ushort_t As[BM * BK];   // 16 KiB, swizzled row-major [128][64]
  __shared__ ushort_t Bs[BN * BK];   // 16 KiB

  const int slot = blockIdx.x;
  const int rows = ws[16 + 3 * slot + 1];
  if (rows == 0) return;
  const int row0 = ws[16 + 3 * slot + 0];
  const int e    = ws[16 + 3 * slot + 2];
  const int c0   = blockIdx.y * BN;

  const int tid  = threadIdx.x;
  const int lane = tid & 63;
  const int wave = tid >> 6;
  const int wm   = (wave >> 1) * 64;
  const int wn   = (wave & 1) * 64;
  const int quad = lane >> 4;
  const int l16  = lane & 15;

  const int* __restrict__ row_token = ws + ROWTOK;

  // Staging: instr t stages 8 rows (wave*32+t*8 ..+7); lane -> row +lane/8.
  // HW puts lane at LDS pos lane&7; we fetch global chunk (lane&7)^(row&7).
  const int lrow8  = lane >> 3;            // 0..7, == row&7 (t*8, wave*32 = 0 mod 8)
  const int gchunk = (lane & 7) ^ lrow8;   // inverse-swizzled global 16B chunk

  const ushort_t* aptr[4];
  const ushort_t* bptr[4];
#pragma unroll
  for (int t = 0; t < 4; ++t) {
    int r  = wave * 32 + t * 8 + lrow8;
    int rc = (r < rows) ? r : (rows - 1);          // clamp tail to a valid row
    aptr[t] = xb + (size_t)row_token[row0 + rc] * KDIM + gchunk * 8;
    bptr[t] = wbm + ((size_t)e * NDIM + c0 + r) * KDIM + gchunk * 8;
  }

  floatx4 zero = {0.f, 0.f, 0.f, 0.f};
  floatx4 acc[4][4];
#pragma unroll
  for (int i = 0; i < 4; ++i)
#pragma unroll
    for (int j = 0; j < 4; ++j) acc[i][j] = zero;

#pragma unroll 4
  for (int kk = 0; kk < KDIM; kk += BK) {
#pragma unroll
    for (int t = 0; t < 4; ++t) {
      __builtin_amdgcn_global_load_lds(
          (gu32*)(const void*)(aptr[t] + kk),
          (lu32*)(void*)(As + (wave * 32 + t * 8) * BK), 16, 0, 0);
      __builtin_amdgcn_global_load_lds(
          (gu32*)(const void*)(bptr[t] + kk),
          (lu32*)(void*)(Bs + (wave * 32 + t * 8) * BK), 16, 0, 0);
    }
    __syncthreads();

#pragma unroll
    for (int k2 = 0; k2 < 2; ++k2) {
      short8 af[4], bf[4];
#pragma unroll
      for (int i = 0; i < 4; ++i) {
        int m = wm + i * 16 + l16;
        af[i] = *(const short8*)(&As[m * BK + (((k2 * 4 + quad) ^ (m & 7)) * 8)]);
      }
#pragma unroll
      for (int j = 0; j < 4; ++j) {
        int n = wn + j * 16 + l16;
        bf[j] = *(const short8*)(&Bs[n * BK + (((k2 * 4 + quad) ^ (n & 7)) * 8)]);
      }
#pragma unroll
      for (int i = 0; i < 4; ++i)
#pragma unroll
        for (int j = 0; j < 4; ++j)
          acc[i][j] = __builtin_amdgcn_mfma_f32_16x16x32_bf16(af[i], bf[j],
                                                              acc[i][j], 0, 0, 0);
    }
    __syncthreads();
  }

#pragma unroll
  for (int i = 0; i < 4; ++i) {
#pragma unroll
    for (int r = 0; r < 4; ++r) {
      int lrow = wm + i * 16 + quad * 4 + r;
      if (lrow < rows) {
        float* o = out + (size_t)(row0 + lrow) * NDIM + c0 + wn + l16;
#pragma unroll
        for (int j = 0; j < 4; ++j) o[j * 16] = acc[i][j][r];
      }
    }
  }
}

// ---------------------------------------------------------------------------
// Fallback (fused convert in-loop) if ws is too small for bf16 staging bufs.
// ---------------------------------------------------------------------------
__global__ __launch_bounds__(256)
void moe_gemm_fallback(const float* __restrict__ x,
                       const float* __restrict__ w,
                       const int* __restrict__ ws,
                       float* __restrict__ out) {
  __shared__ ushort_t As[BM * BK];
  __shared__ ushort_t Bs[BN * BK];

  const int slot = blockIdx.x;
  const int rows = ws[16 + 3 * slot + 1];
  if (rows == 0) return;
  const int row0 = ws[16 + 3 * slot + 0];
  const int e    = ws[16 + 3 * slot + 2];
  const int c0   = blockIdx.y * BN;

  const int tid  = threadIdx.x;
  const int lane = tid & 63;
  const int wave = tid >> 6;
  const int wm   = (wave >> 1) * 64;
  const int wn   = (wave & 1) * 64;
  const int quad = lane >> 4;
  const int l16  = lane & 15;

  const int* __restrict__ row_token = ws + ROWTOK;

  const int f4    = tid & 15;
  const int rbase = tid >> 4;
  const int swz   = (f4 >> 1) ^ (rbase & 7);
  const int wroff = rbase * BK + swz * 8 + (f4 & 1) * 4;

  const float* __restrict__ wb = w + ((size_t)e * NDIM + c0) * KDIM;
  const float* pA[8];
#pragma unroll
  for (int i = 0; i < 8; ++i) {
    int r = rbase + i * 16;
    pA[i] = (r < rows) ? (x + (size_t)row_token[row0 + r] * KDIM + f4 * 4)
                       : nullptr;
  }
  const float* pB0 = wb + (size_t)rbase * KDIM + f4 * 4;

  floatx4 zero = {0.f, 0.f, 0.f, 0.f};
  floatx4 acc[4][4];
#pragma unroll
  for (int i = 0; i < 4; ++i)
#pragma unroll
    for (int j = 0; j < 4; ++j) acc[i][j] = zero;

#pragma unroll 1
  for (int kk = 0; kk < KDIM; kk += BK) {
#pragma unroll
    for (int i = 0; i < 8; ++i) {
      float4 v = {0.f, 0.f, 0.f, 0.f};
      if (pA[i]) v = *(const float4*)(pA[i] + kk);
      union { __hip_bfloat162 h; unsigned int u; } lo, hi;
      lo.h = __float22bfloat162_rn(make_float2(v.x, v.y));
      hi.h = __float22bfloat162_rn(make_float2(v.z, v.w));
      uint2 u2; u2.x = lo.u; u2.y = hi.u;
      *(uint2*)(&As[wroff + i * 16 * BK]) = u2;
    }
#pragma unroll
    for (int i = 0; i < 8; ++i) {
      float4 v = *(const float4*)(pB0 + (size_t)i * 16 * KDIM + kk);
      union { __hip_bfloat162 h; unsigned int u; } lo, hi;
      lo.h = __float22bfloat162_rn(make_float2(v.x, v.y));
      hi.h = __float22bfloat162_rn(make_float2(v.z, v.w));
      uint2 u2; u2.x = lo.u; u2.y = hi.u;
      *(uint2*)(&Bs[wroff + i * 16 * BK]) = u2;
    }
    __syncthreads();
#pragma unroll
    for (int k2 = 0; k2 < 2; ++k2) {
      short8 af[4], bf[4];
#pragma unroll
      for (int i = 0; i < 4; ++i) {
        int m = wm + i * 16 + l16;
        af[i] = *(const short8*)(&As[m * BK + ((k2 * 4 + quad) ^ (m & 7)) * 8]);
      }
#pragma unroll
      for (int j = 0; j < 4; ++j) {
        int n = wn + j * 16 + l16;
        bf[j] = *(const short8*)(&Bs[n * BK + ((k2 * 4 + quad) ^ (n & 7)) * 8]);
      }
#pragma unroll
      for (int i = 0; i < 4; ++i)
#pragma unroll
        for (int j = 0; j < 4; ++j)
          acc[i][j] = __builtin_amdgcn_mfma_f32_16x16x32_bf16(af[i], bf[j],
                                                              acc[i][j], 0, 0, 0);
    }
    __syncthreads();
  }

#pragma unroll
  for (int i = 0; i < 4; ++i) {
#pragma unroll
    for (int r = 0; r < 4; ++r) {
      int lrow = wm + i * 16 + quad * 4 + r;
      if (lrow < rows) {
        float* o = out + (size_t)(row0 + lrow) * NDIM + c0 + wn + l16;
#pragma unroll
        for (int j = 0; j < 4; ++j) o[j * 16] = acc[i][j][r];
      }
    }
  }
}

// ---------------------------------------------------------------------------
extern "C" void kernel_launch(void* const* d_in, const int* in_sizes, int n_in,
                              void* d_out, int out_size, void* d_ws, size_t ws_size,
                              hipStream_t stream) {
  const float* x       = (const float*)d_in[0];   // [8192,1024] f32
  const float* weights = (const float*)d_in[1];   // [8,1024,1024] f32
  const int*   scatter = (const int*)d_in[2];     // [8192,2] i32
  const int*   splits  = (const int*)d_in[3];     // [8] i32
  float*       out     = (float*)d_out;           // [16384,1024] f32
  int*         ws      = (int*)d_ws;

  moe_setup<<<dim3(MOUT / 256), dim3(256), 0, stream>>>(scatter, splits, ws);

  if (ws_size >= WS_NEED) {
    ushort_t* xb = (ushort_t*)((char*)d_ws + XB_OFF);
    ushort_t* wb = (ushort_t*)((char*)d_ws + WB_OFF);
    convert_both<<<dim3(2048), dim3(256), 0, stream>>>(x, weights, xb, wb);
    moe_gemm_fast<<<dim3(MAXT, NDIM / BN), dim3(256), 0, stream>>>(xb, wb, ws, out);
  } else {
    moe_gemm_fallback<<<dim3(MAXT, NDIM / BN), dim3(256), 0, stream>>>(x, weights,
                                                                       ws, out);
  }
}